// Round 1
// baseline (342.279 us; speedup 1.0000x reference)
//
#include <hip/hip_runtime.h>
#include <hip/hip_bf16.h>

// Problem dims
#define NB 32
#define NT 64
#define NJ 22
#define ND 512
#define NH 8
#define NC 128
#define NDH 64

typedef __attribute__((ext_vector_type(8))) short s16x8;   // 8 bf16 (4 VGPRs)
typedef __attribute__((ext_vector_type(4))) float fx4;     // MFMA accumulator

static __device__ __forceinline__ unsigned short f2bf(float f) {
    unsigned u = __builtin_bit_cast(unsigned, f);
    u += 0x7fffu + ((u >> 16) & 1u);   // RNE
    return (unsigned short)(u >> 16);
}

static __device__ __forceinline__ fx4 mfma16(s16x8 a, s16x8 b, fx4 c) {
    return __builtin_amdgcn_mfma_f32_16x16x32_bf16(a, b, c, 0, 0, 0);
}

// C[M,Ncols=512] = A[M,K=512] @ W[512,512] + bias, output bf16 or f32.
// A is f32 or bf16(ushort). 64x64 tile, 4 waves (2x2), K-step 32.
// grid.z = joint index with per-joint strides (0 for shared weights).
template <typename TA, typename TC>
__global__ __launch_bounds__(256) void gemm_bias_k(
    const TA* __restrict__ A, long lda,
    const float* __restrict__ W,
    const float* __restrict__ bias,
    TC* __restrict__ C, long ldc,
    long jsA, long jsW, long jsB, long jsC)
{
    __shared__ unsigned short As[64][40];   // [m][k] bf16, +8 pad (16B-aligned rows)
    __shared__ unsigned short Bs[64][40];   // [n][k] bf16 (W transposed)

    const int tid = threadIdx.x;
    const long j = blockIdx.z;
    A    += (long)blockIdx.x * 64 * lda + j * jsA;
    W    += j * jsW + blockIdx.y * 64;
    bias += j * jsB + blockIdx.y * 64;
    C    += (long)blockIdx.x * 64 * ldc + j * jsC + blockIdx.y * 64;

    const int wid = tid >> 6;
    const int lane = tid & 63;
    const int wm = wid >> 1, wn = wid & 1;
    const int lr = lane & 15, lk = lane >> 4;

    const int arow = tid >> 2, ac0 = (tid & 3) * 8;   // A stage: 8 elems/thread
    const int bk   = tid >> 3, bc0 = (tid & 7) * 8;   // W stage: 8 elems/thread

    fx4 acc[2][2] = {};

    for (int kt = 0; kt < 512; kt += 32) {
        // ---- stage A tile (64x32) as bf16 ----
        {
            const TA* src = A + (long)arow * lda + kt + ac0;
            unsigned short tmp[8];
            if constexpr (sizeof(TA) == 4) {
                const float4 p0 = *reinterpret_cast<const float4*>(src);
                const float4 p1 = *reinterpret_cast<const float4*>(src + 4);
                tmp[0]=f2bf(p0.x); tmp[1]=f2bf(p0.y); tmp[2]=f2bf(p0.z); tmp[3]=f2bf(p0.w);
                tmp[4]=f2bf(p1.x); tmp[5]=f2bf(p1.y); tmp[6]=f2bf(p1.z); tmp[7]=f2bf(p1.w);
            } else {
                *reinterpret_cast<s16x8*>(tmp) =
                    *reinterpret_cast<const s16x8*>(src);
            }
            *reinterpret_cast<s16x8*>(&As[arow][ac0]) = *reinterpret_cast<s16x8*>(tmp);
        }
        // ---- stage W tile (32x64) transposed -> Bs[n][k] ----
        {
            const float* wsrc = W + (long)(kt + bk) * ND + bc0;
            const float4 q0 = *reinterpret_cast<const float4*>(wsrc);
            const float4 q1 = *reinterpret_cast<const float4*>(wsrc + 4);
            const float wv[8] = {q0.x,q0.y,q0.z,q0.w,q1.x,q1.y,q1.z,q1.w};
            #pragma unroll
            for (int e = 0; e < 8; ++e) Bs[bc0 + e][bk] = f2bf(wv[e]);
        }
        __syncthreads();
        // ---- MFMA: each wave 32x32 = 2x2 fragments ----
        s16x8 a0 = *reinterpret_cast<const s16x8*>(&As[wm*32      + lr][lk*8]);
        s16x8 a1 = *reinterpret_cast<const s16x8*>(&As[wm*32 + 16 + lr][lk*8]);
        s16x8 b0 = *reinterpret_cast<const s16x8*>(&Bs[wn*32      + lr][lk*8]);
        s16x8 b1 = *reinterpret_cast<const s16x8*>(&Bs[wn*32 + 16 + lr][lk*8]);
        acc[0][0] = mfma16(a0, b0, acc[0][0]);
        acc[0][1] = mfma16(a0, b1, acc[0][1]);
        acc[1][0] = mfma16(a1, b0, acc[1][0]);
        acc[1][1] = mfma16(a1, b1, acc[1][1]);
        __syncthreads();
    }

    // ---- epilogue: bias + store (C/D layout: col=lane&15, row=(lane>>4)*4+r) ----
    #pragma unroll
    for (int am = 0; am < 2; ++am)
    #pragma unroll
    for (int bn = 0; bn < 2; ++bn) {
        const int col = wn*32 + bn*16 + lr;
        const float bv = bias[col];
        #pragma unroll
        for (int r = 0; r < 4; ++r) {
            const int row = wm*32 + am*16 + lk*4 + r;
            const float val = acc[am][bn][r] + bv;
            if constexpr (sizeof(TC) == 2)
                reinterpret_cast<unsigned short*>(C)[(long)row*ldc + col] = f2bf(val);
            else
                reinterpret_cast<float*>(C)[(long)row*ldc + col] = val;
        }
    }
}

// Fused attention per (b, joint, head): S=Q K^T/8, softmax over C, O = P V.
// Block = 256 threads (4 waves); wave w owns 16 query rows.
__global__ __launch_bounds__(256) void attn_k(
    const unsigned short* __restrict__ q,   // bf16 [B,T,N,D]
    const unsigned short* __restrict__ k,   // bf16 [B,C,D]
    const unsigned short* __restrict__ v,   // bf16 [B,C,D]
    unsigned short* __restrict__ o)         // bf16 [B,T,N,D]
{
    __shared__ unsigned short Qs[64][72];    // [t][dh]
    __shared__ unsigned short Ks[128][72];   // [c][dh]
    __shared__ unsigned short Vt[64][136];   // [dh][c]  (V transposed)
    __shared__ unsigned short Ps[64][136];   // [t][c]   bf16 probabilities

    const int tid = threadIdx.x;
    const int bid = blockIdx.x;
    const int h = bid & 7;
    const int n = (bid >> 3) % NJ;
    const int b = bid / (NJ * NH);

    // ---- stage Q (64x64) ----
    {
        const int row = tid >> 2, c0 = (tid & 3) * 16;
        const unsigned short* qb = q + (((long)b*NT + row)*NJ + n)*ND + h*NDH + c0;
        *reinterpret_cast<s16x8*>(&Qs[row][c0])     = *reinterpret_cast<const s16x8*>(qb);
        *reinterpret_cast<s16x8*>(&Qs[row][c0 + 8]) = *reinterpret_cast<const s16x8*>(qb + 8);
    }
    // ---- stage K (128x64) ----
    {
        const int row = tid >> 1, c0 = (tid & 1) * 32;
        const unsigned short* kb = k + ((long)b*NC + row)*ND + h*NDH + c0;
        #pragma unroll
        for (int i = 0; i < 4; ++i)
            *reinterpret_cast<s16x8*>(&Ks[row][c0 + i*8]) =
                *reinterpret_cast<const s16x8*>(kb + i*8);
    }
    // ---- stage V transposed: Vt[dh][c] ----
    {
        const int d = tid & 63;
        const int c0 = tid >> 6;   // 0..3
        const unsigned short* vb = v + ((long)b*NC)*ND + h*NDH + d;
        #pragma unroll
        for (int i = 0; i < 32; ++i) {
            const int c = c0 + i*4;
            Vt[d][c] = vb[(long)c*ND];
        }
    }
    __syncthreads();

    const int wid = tid >> 6;
    const int lane = tid & 63;
    const int lr = lane & 15, lk = lane >> 4;
    const int trow0 = wid * 16;   // this wave's 16 query rows

    // ---- S = Q K^T : per wave 16 x 128 (8 col-frags, K=64 in 2 steps) ----
    fx4 s[8] = {};
    {
        s16x8 aq0 = *reinterpret_cast<const s16x8*>(&Qs[trow0 + lr][lk*8]);
        s16x8 aq1 = *reinterpret_cast<const s16x8*>(&Qs[trow0 + lr][32 + lk*8]);
        #pragma unroll
        for (int f = 0; f < 8; ++f) {
            s16x8 b0 = *reinterpret_cast<const s16x8*>(&Ks[f*16 + lr][lk*8]);
            s16x8 b1 = *reinterpret_cast<const s16x8*>(&Ks[f*16 + lr][32 + lk*8]);
            s[f] = mfma16(aq0, b0, s[f]);
            s[f] = mfma16(aq1, b1, s[f]);
        }
    }

    // ---- in-register softmax (rows live across 16-lane groups) ----
    // lane holds rows trow0 + lk*4 + r, cols f*16 + lr
    #pragma unroll
    for (int r = 0; r < 4; ++r) {
        float m = -1e30f;
        #pragma unroll
        for (int f = 0; f < 8; ++f) m = fmaxf(m, s[f][r]);
        #pragma unroll
        for (int off = 1; off < 16; off <<= 1) m = fmaxf(m, __shfl_xor(m, off));
        float p[8]; float sum = 0.f;
        #pragma unroll
        for (int f = 0; f < 8; ++f) { p[f] = expf(0.125f * (s[f][r] - m)); sum += p[f]; }
        #pragma unroll
        for (int off = 1; off < 16; off <<= 1) sum += __shfl_xor(sum, off);
        const float inv = 1.0f / sum;
        const int row = trow0 + lk*4 + r;
        #pragma unroll
        for (int f = 0; f < 8; ++f) Ps[row][f*16 + lr] = f2bf(p[f] * inv);
    }
    __syncthreads();   // safety: P visible before PV (same-wave rows, but cheap)

    // ---- O = P V : per wave 16 x 64 (4 dh-frags, K=128 in 4 steps) ----
    fx4 oacc[4] = {};
    #pragma unroll
    for (int kt = 0; kt < 4; ++kt) {
        s16x8 ap = *reinterpret_cast<const s16x8*>(&Ps[trow0 + lr][kt*32 + lk*8]);
        #pragma unroll
        for (int bn = 0; bn < 4; ++bn) {
            s16x8 bv = *reinterpret_cast<const s16x8*>(&Vt[bn*16 + lr][kt*32 + lk*8]);
            oacc[bn] = mfma16(ap, bv, oacc[bn]);
        }
    }
    // ---- store O ----
    #pragma unroll
    for (int bn = 0; bn < 4; ++bn) {
        #pragma unroll
        for (int r = 0; r < 4; ++r) {
            const int t  = trow0 + lk*4 + r;
            const int dh = bn*16 + lr;
            o[(((long)b*NT + t)*NJ + n)*ND + h*NDH + dh] = f2bf(oacc[bn][r]);
        }
    }
}

extern "C" void kernel_launch(void* const* d_in, const int* in_sizes, int n_in,
                              void* d_out, int out_size, void* d_ws, size_t ws_size,
                              hipStream_t stream)
{
    const float* x    = (const float*)d_in[0];
    const float* ctx  = (const float*)d_in[1];
    const float* Wq   = (const float*)d_in[2];
    const float* bq   = (const float*)d_in[3];
    const float* Wk   = (const float*)d_in[4];
    const float* bk   = (const float*)d_in[5];
    const float* Wv   = (const float*)d_in[6];
    const float* bv   = (const float*)d_in[7];
    const float* Wout = (const float*)d_in[8];
    const float* bout = (const float*)d_in[9];
    float* out = (float*)d_out;

    // workspace: bf16 intermediates
    unsigned short* qbf = (unsigned short*)d_ws;                   // [B,T,N,D]  45056*512
    unsigned short* kbf = qbf + (size_t)45056 * 512;               // [B,C,D]
    unsigned short* vbf = kbf + (size_t)4096 * 512;                // [B,C,D]
    unsigned short* obf = vbf + (size_t)4096 * 512;                // [B,T,N,D]

    // 1) Q projection: per-joint GEMM (M = B*T = 2048 rows, strided by joint)
    gemm_bias_k<float, unsigned short><<<dim3(2048/64, 8, NJ), 256, 0, stream>>>(
        x, (long)NJ*ND, Wq, bq, qbf, (long)NJ*ND,
        (long)ND, (long)ND*ND, (long)ND, (long)ND);

    // 2,3) K/V projections: M = B*C = 4096
    gemm_bias_k<float, unsigned short><<<dim3(4096/64, 8, 1), 256, 0, stream>>>(
        ctx, ND, Wk, bk, kbf, ND, 0, 0, 0, 0);
    gemm_bias_k<float, unsigned short><<<dim3(4096/64, 8, 1), 256, 0, stream>>>(
        ctx, ND, Wv, bv, vbf, ND, 0, 0, 0, 0);

    // 4) fused attention: one block per (b, joint, head)
    attn_k<<<dim3(NB*NJ*NH), 256, 0, stream>>>(qbf, kbf, vbf, obf);

    // 5) output projection: M = B*T*N = 45056, f32 output
    gemm_bias_k<unsigned short, float><<<dim3(45056/64, 8, 1), 256, 0, stream>>>(
        obf, ND, Wout, bout, out, ND, 0, 0, 0, 0);
}

// Round 2
// 231.174 us; speedup vs baseline: 1.4806x; 1.4806x over previous
//
#include <hip/hip_runtime.h>
#include <hip/hip_bf16.h>

// Problem dims
#define NB 32
#define NT 64
#define NJ 22
#define ND 512
#define NH 8
#define NC 128
#define NDH 64

typedef __attribute__((ext_vector_type(8))) short s16x8;   // 8 bf16 (4 VGPRs)
typedef __attribute__((ext_vector_type(4))) float fx4;     // MFMA accumulator

static __device__ __forceinline__ unsigned short f2bf(float f) {
    unsigned u = __builtin_bit_cast(unsigned, f);
    u += 0x7fffu + ((u >> 16) & 1u);   // RNE
    return (unsigned short)(u >> 16);
}

static __device__ __forceinline__ fx4 mfma16(s16x8 a, s16x8 b, fx4 c) {
    return __builtin_amdgcn_mfma_f32_16x16x32_bf16(a, b, c, 0, 0, 0);
}

// async global->LDS, 16B per lane. LDS dest is wave-uniform base; HW adds lane*16.
static __device__ __forceinline__ void gload16(const void* g, void* l) {
    __builtin_amdgcn_global_load_lds(
        (const __attribute__((address_space(1))) void*)g,
        (__attribute__((address_space(3))) void*)l,
        16, 0, 0);
}

// ---------------------------------------------------------------------------
// f32 -> bf16 convert, 8 elems/thread, exact grid (count % 2048 == 0)
__global__ __launch_bounds__(256) void convx_k(const float* __restrict__ src,
                                               unsigned short* __restrict__ dst)
{
    const long i = ((long)blockIdx.x * 256 + threadIdx.x) * 8;
    const float4 a = *reinterpret_cast<const float4*>(src + i);
    const float4 b = *reinterpret_cast<const float4*>(src + i + 4);
    unsigned short t[8];
    t[0]=f2bf(a.x); t[1]=f2bf(a.y); t[2]=f2bf(a.z); t[3]=f2bf(a.w);
    t[4]=f2bf(b.x); t[5]=f2bf(b.y); t[6]=f2bf(b.z); t[7]=f2bf(b.w);
    *reinterpret_cast<s16x8*>(dst + i) = *reinterpret_cast<s16x8*>(t);
}

// ---------------------------------------------------------------------------
// Wt[n][k] = (bf16) W[k][n] for 512x512 matrices; blockIdx.z selects matrix.
__global__ __launch_bounds__(256) void twconv_k(const float* __restrict__ W,
                                                unsigned short* __restrict__ Wt,
                                                long zsrc, long zdst)
{
    __shared__ float T[64][65];
    const int tid = threadIdx.x;
    W  += blockIdx.z * zsrc + (long)blockIdx.x * 64 * 512 + blockIdx.y * 64;
    Wt += blockIdx.z * zdst + (long)blockIdx.y * 64 * 512 + blockIdx.x * 64;
    const int r = tid >> 2, c0 = (tid & 3) * 16;
    #pragma unroll
    for (int i = 0; i < 4; ++i) {
        const float4 p = *reinterpret_cast<const float4*>(W + (long)r * 512 + c0 + i*4);
        T[r][c0 + i*4 + 0] = p.x; T[r][c0 + i*4 + 1] = p.y;
        T[r][c0 + i*4 + 2] = p.z; T[r][c0 + i*4 + 3] = p.w;
    }
    __syncthreads();
    unsigned short o[16];
    #pragma unroll
    for (int i = 0; i < 16; ++i) o[i] = f2bf(T[c0 + i][r]);
    *reinterpret_cast<s16x8*>(Wt + (long)r * 512 + c0)     = *reinterpret_cast<s16x8*>(o);
    *reinterpret_cast<s16x8*>(Wt + (long)r * 512 + c0 + 8) = *reinterpret_cast<s16x8*>(o + 8);
}

// ---------------------------------------------------------------------------
// m97-structure bf16 GEMM: C[M,512] = A[M,512] @ Bt^T + bias.
// Bt is [n][k] (pre-transposed). 128x128 tile, BK=64, 4 waves (2x2), 4x4 frags.
// global_load_lds width-16 staging, linear LDS, 2-barrier loop.
template <typename TC>
__global__ __launch_bounds__(256) void gemm128_k(
    const unsigned short* __restrict__ A, long lda,
    const unsigned short* __restrict__ Bt,
    const float* __restrict__ bias,
    TC* __restrict__ C, long ldc,
    long jsA, long jsW, long jsB, long jsC)
{
    __shared__ unsigned short As[128][64];   // [m][k] linear (global_load_lds dest)
    __shared__ unsigned short Bs[128][64];   // [n][k] linear

    const int tid = threadIdx.x;
    const int w = tid >> 6, lane = tid & 63;
    const long j = blockIdx.z;

    A    += (long)blockIdx.x * 128 * lda + j * jsA;
    Bt   += j * jsW + (long)blockIdx.y * 128 * 512;
    bias += j * jsB + blockIdx.y * 128;
    C    += (long)blockIdx.x * 128 * ldc + j * jsC + blockIdx.y * 128;

    // staging map: issue it covers rows it*32 + w*8 + (lane>>3), cols (lane&7)*8
    const int srow = lane >> 3;
    const int scol = (lane & 7) * 8;
    const unsigned short* Ag = A  + (long)(w*8 + srow) * lda + scol;
    const unsigned short* Bg = Bt + (long)(w*8 + srow) * 512 + scol;
    char* Al = (char*)As + w * 1024;
    char* Bl = (char*)Bs + w * 1024;

    const int lr = lane & 15, lk = lane >> 4;
    const int wm = w >> 1, wn = w & 1;

    fx4 acc[4][4] = {};

    for (int kt = 0; kt < 512; kt += 64) {
        #pragma unroll
        for (int it = 0; it < 4; ++it)
            gload16(Ag + (long)it * 32 * lda + kt, Al + it * 4096);
        #pragma unroll
        for (int it = 0; it < 4; ++it)
            gload16(Bg + (long)it * 32 * 512 + kt, Bl + it * 4096);
        __syncthreads();   // drains vmcnt -> LDS tiles ready
        #pragma unroll
        for (int ks = 0; ks < 2; ++ks) {
            s16x8 a[4], b[4];
            #pragma unroll
            for (int m = 0; m < 4; ++m)
                a[m] = *reinterpret_cast<const s16x8*>(&As[wm*64 + m*16 + lr][ks*32 + lk*8]);
            #pragma unroll
            for (int n = 0; n < 4; ++n)
                b[n] = *reinterpret_cast<const s16x8*>(&Bs[wn*64 + n*16 + lr][ks*32 + lk*8]);
            #pragma unroll
            for (int m = 0; m < 4; ++m)
                #pragma unroll
                for (int n = 0; n < 4; ++n)
                    acc[m][n] = mfma16(a[m], b[n], acc[m][n]);
        }
        __syncthreads();
    }

    // epilogue: C/D layout col=lane&15, row=(lane>>4)*4+r
    #pragma unroll
    for (int n = 0; n < 4; ++n) {
        const int col = wn*64 + n*16 + lr;
        const float bv = bias[col];
        #pragma unroll
        for (int m = 0; m < 4; ++m) {
            #pragma unroll
            for (int r = 0; r < 4; ++r) {
                const int row = wm*64 + m*16 + lk*4 + r;
                const float val = acc[m][n][r] + bv;
                if constexpr (sizeof(TC) == 2)
                    reinterpret_cast<unsigned short*>(C)[(long)row*ldc + col] = f2bf(val);
                else
                    reinterpret_cast<float*>(C)[(long)row*ldc + col] = val;
            }
        }
    }
}

// ---------------------------------------------------------------------------
// Fused attention per (b, joint, head): S=Q K^T/8, softmax over C, O = P V.
__global__ __launch_bounds__(256) void attn_k(
    const unsigned short* __restrict__ q,   // bf16 [B,T,N,D]
    const unsigned short* __restrict__ k,   // bf16 [B,C,D]
    const unsigned short* __restrict__ v,   // bf16 [B,C,D]
    unsigned short* __restrict__ o)         // bf16 [B,T,N,D]
{
    __shared__ unsigned short Qs[64][72];
    __shared__ unsigned short Ks[128][72];
    __shared__ unsigned short Vt[64][136];
    __shared__ unsigned short Ps[64][136];

    const int tid = threadIdx.x;
    const int bid = blockIdx.x;
    const int h = bid & 7;
    const int n = (bid >> 3) % NJ;
    const int b = bid / (NJ * NH);

    {
        const int row = tid >> 2, c0 = (tid & 3) * 16;
        const unsigned short* qb = q + (((long)b*NT + row)*NJ + n)*ND + h*NDH + c0;
        *reinterpret_cast<s16x8*>(&Qs[row][c0])     = *reinterpret_cast<const s16x8*>(qb);
        *reinterpret_cast<s16x8*>(&Qs[row][c0 + 8]) = *reinterpret_cast<const s16x8*>(qb + 8);
    }
    {
        const int row = tid >> 1, c0 = (tid & 1) * 32;
        const unsigned short* kb = k + ((long)b*NC + row)*ND + h*NDH + c0;
        #pragma unroll
        for (int i = 0; i < 4; ++i)
            *reinterpret_cast<s16x8*>(&Ks[row][c0 + i*8]) =
                *reinterpret_cast<const s16x8*>(kb + i*8);
    }
    {
        const int d = tid & 63;
        const int c0 = tid >> 6;
        const unsigned short* vb = v + ((long)b*NC)*ND + h*NDH + d;
        #pragma unroll
        for (int i = 0; i < 32; ++i) {
            const int c = c0 + i*4;
            Vt[d][c] = vb[(long)c*ND];
        }
    }
    __syncthreads();

    const int wid = tid >> 6;
    const int lane = tid & 63;
    const int lr = lane & 15, lk = lane >> 4;
    const int trow0 = wid * 16;

    fx4 s[8] = {};
    {
        s16x8 aq0 = *reinterpret_cast<const s16x8*>(&Qs[trow0 + lr][lk*8]);
        s16x8 aq1 = *reinterpret_cast<const s16x8*>(&Qs[trow0 + lr][32 + lk*8]);
        #pragma unroll
        for (int f = 0; f < 8; ++f) {
            s16x8 b0 = *reinterpret_cast<const s16x8*>(&Ks[f*16 + lr][lk*8]);
            s16x8 b1 = *reinterpret_cast<const s16x8*>(&Ks[f*16 + lr][32 + lk*8]);
            s[f] = mfma16(aq0, b0, s[f]);
            s[f] = mfma16(aq1, b1, s[f]);
        }
    }

    #pragma unroll
    for (int r = 0; r < 4; ++r) {
        float m = -1e30f;
        #pragma unroll
        for (int f = 0; f < 8; ++f) m = fmaxf(m, s[f][r]);
        #pragma unroll
        for (int off = 1; off < 16; off <<= 1) m = fmaxf(m, __shfl_xor(m, off));
        float p[8]; float sum = 0.f;
        #pragma unroll
        for (int f = 0; f < 8; ++f) { p[f] = expf(0.125f * (s[f][r] - m)); sum += p[f]; }
        #pragma unroll
        for (int off = 1; off < 16; off <<= 1) sum += __shfl_xor(sum, off);
        const float inv = 1.0f / sum;
        const int row = trow0 + lk*4 + r;
        #pragma unroll
        for (int f = 0; f < 8; ++f) Ps[row][f*16 + lr] = f2bf(p[f] * inv);
    }
    __syncthreads();

    fx4 oacc[4] = {};
    #pragma unroll
    for (int kt = 0; kt < 4; ++kt) {
        s16x8 ap = *reinterpret_cast<const s16x8*>(&Ps[trow0 + lr][kt*32 + lk*8]);
        #pragma unroll
        for (int bn = 0; bn < 4; ++bn) {
            s16x8 bv = *reinterpret_cast<const s16x8*>(&Vt[bn*16 + lr][kt*32 + lk*8]);
            oacc[bn] = mfma16(ap, bv, oacc[bn]);
        }
    }
    #pragma unroll
    for (int bn = 0; bn < 4; ++bn) {
        #pragma unroll
        for (int r = 0; r < 4; ++r) {
            const int t  = trow0 + lk*4 + r;
            const int dh = bn*16 + lr;
            o[(((long)b*NT + t)*NJ + n)*ND + h*NDH + dh] = f2bf(oacc[bn][r]);
        }
    }
}

extern "C" void kernel_launch(void* const* d_in, const int* in_sizes, int n_in,
                              void* d_out, int out_size, void* d_ws, size_t ws_size,
                              hipStream_t stream)
{
    const float* x    = (const float*)d_in[0];
    const float* ctx  = (const float*)d_in[1];
    const float* Wq   = (const float*)d_in[2];
    const float* bq   = (const float*)d_in[3];
    const float* Wk   = (const float*)d_in[4];
    const float* bk   = (const float*)d_in[5];
    const float* Wv   = (const float*)d_in[6];
    const float* bv   = (const float*)d_in[7];
    const float* Wout = (const float*)d_in[8];
    const float* bout = (const float*)d_in[9];
    float* out = (float*)d_out;

    const size_t NX  = (size_t)45056 * 512;   // x / q / o elements
    const size_t NKV = (size_t)4096 * 512;    // ctx / k / v elements
    const size_t NW  = (size_t)512 * 512;     // one weight matrix

    // workspace layout (ushort elems). obf aliases xbf (x dead after gemm Q).
    unsigned short* xbf   = (unsigned short*)d_ws;     // also obf
    unsigned short* qbf   = xbf   + NX;
    unsigned short* cbf   = qbf   + NX;                // ctx bf16
    unsigned short* kbf   = cbf   + NKV;
    unsigned short* vbf   = kbf   + NKV;
    unsigned short* WqT   = vbf   + NKV;               // 22 matrices, [n][k]
    unsigned short* WkT   = WqT   + 22 * NW;
    unsigned short* WvT   = WkT   + NW;
    unsigned short* WoutT = WvT   + NW;
    unsigned short* obf   = xbf;

    // 1) converts
    convx_k<<<dim3(NX / 2048), 256, 0, stream>>>(x, xbf);
    convx_k<<<dim3(NKV / 2048), 256, 0, stream>>>(ctx, cbf);
    twconv_k<<<dim3(8, 8, 22), 256, 0, stream>>>(Wq,   WqT,   (long)NW, (long)NW);
    twconv_k<<<dim3(8, 8, 1),  256, 0, stream>>>(Wk,   WkT,   0, 0);
    twconv_k<<<dim3(8, 8, 1),  256, 0, stream>>>(Wv,   WvT,   0, 0);
    twconv_k<<<dim3(8, 8, 1),  256, 0, stream>>>(Wout, WoutT, 0, 0);

    // 2) Q projection: per-joint (M=2048 rows, row stride NJ*ND)
    gemm128_k<unsigned short><<<dim3(16, 4, NJ), 256, 0, stream>>>(
        xbf, (long)NJ*ND, WqT, bq, qbf, (long)NJ*ND,
        (long)ND, (long)NW, (long)ND, (long)ND);

    // 3,4) K/V projections: M = 4096
    gemm128_k<unsigned short><<<dim3(32, 4, 1), 256, 0, stream>>>(
        cbf, ND, WkT, bk, kbf, ND, 0, 0, 0, 0);
    gemm128_k<unsigned short><<<dim3(32, 4, 1), 256, 0, stream>>>(
        cbf, ND, WvT, bv, vbf, ND, 0, 0, 0, 0);

    // 5) fused attention: one block per (b, joint, head)
    attn_k<<<dim3(NB*NJ*NH), 256, 0, stream>>>(qbf, kbf, vbf, obf);

    // 6) output projection: M = 45056, f32 output
    gemm128_k<float><<<dim3(45056/128, 4, 1), 256, 0, stream>>>(
        obf, ND, WoutT, bout, out, ND, 0, 0, 0, 0);
}

// Round 3
// 213.576 us; speedup vs baseline: 1.6026x; 1.0824x over previous
//
#include <hip/hip_runtime.h>
#include <hip/hip_bf16.h>

// Problem dims
#define NB 32
#define NT 64
#define NJ 22
#define ND 512
#define NH 8
#define NC 128
#define NDH 64
#define NR 1408   // T*N rows per (b)

typedef __attribute__((ext_vector_type(8))) short s16x8;   // 8 bf16 (4 VGPRs)
typedef __attribute__((ext_vector_type(4))) float fx4;     // MFMA accumulator

static __device__ __forceinline__ unsigned short f2bf(float f) {
    unsigned u = __builtin_bit_cast(unsigned, f);
    u += 0x7fffu + ((u >> 16) & 1u);   // RNE
    return (unsigned short)(u >> 16);
}

static __device__ __forceinline__ fx4 mfma16(s16x8 a, s16x8 b, fx4 c) {
    return __builtin_amdgcn_mfma_f32_16x16x32_bf16(a, b, c, 0, 0, 0);
}

// async global->LDS, 16B per lane. LDS dest is wave-uniform base; HW adds lane*16.
static __device__ __forceinline__ void gload16(const void* g, void* l) {
    __builtin_amdgcn_global_load_lds(
        (const __attribute__((address_space(1))) void*)g,
        (__attribute__((address_space(3))) void*)l,
        16, 0, 0);
}

// ---------------------------------------------------------------------------
// f32 -> bf16 convert, 8 elems/thread, exact grid (count % 2048 == 0)
__global__ __launch_bounds__(256) void convx_k(const float* __restrict__ src,
                                               unsigned short* __restrict__ dst)
{
    const long i = ((long)blockIdx.x * 256 + threadIdx.x) * 8;
    const float4 a = *reinterpret_cast<const float4*>(src + i);
    const float4 b = *reinterpret_cast<const float4*>(src + i + 4);
    unsigned short t[8];
    t[0]=f2bf(a.x); t[1]=f2bf(a.y); t[2]=f2bf(a.z); t[3]=f2bf(a.w);
    t[4]=f2bf(b.x); t[5]=f2bf(b.y); t[6]=f2bf(b.z); t[7]=f2bf(b.w);
    *reinterpret_cast<s16x8*>(dst + i) = *reinterpret_cast<s16x8*>(t);
}

// ---------------------------------------------------------------------------
// Wt[n][k] = (bf16) W[k][n] for 512x512 matrices; blockIdx.z selects matrix.
__global__ __launch_bounds__(256) void twconv_k(const float* __restrict__ W,
                                                unsigned short* __restrict__ Wt,
                                                long zsrc, long zdst)
{
    __shared__ float T[64][65];
    const int tid = threadIdx.x;
    W  += blockIdx.z * zsrc + (long)blockIdx.x * 64 * 512 + blockIdx.y * 64;
    Wt += blockIdx.z * zdst + (long)blockIdx.y * 64 * 512 + blockIdx.x * 64;
    const int r = tid >> 2, c0 = (tid & 3) * 16;
    #pragma unroll
    for (int i = 0; i < 4; ++i) {
        const float4 p = *reinterpret_cast<const float4*>(W + (long)r * 512 + c0 + i*4);
        T[r][c0 + i*4 + 0] = p.x; T[r][c0 + i*4 + 1] = p.y;
        T[r][c0 + i*4 + 2] = p.z; T[r][c0 + i*4 + 3] = p.w;
    }
    __syncthreads();
    unsigned short o[16];
    #pragma unroll
    for (int i = 0; i < 16; ++i) o[i] = f2bf(T[c0 + i][r]);
    *reinterpret_cast<s16x8*>(Wt + (long)r * 512 + c0)     = *reinterpret_cast<s16x8*>(o);
    *reinterpret_cast<s16x8*>(Wt + (long)r * 512 + c0 + 8) = *reinterpret_cast<s16x8*>(o + 8);
}

// ---------------------------------------------------------------------------
// m97-structure bf16 GEMM: C[M,512] = A[M,512] @ Bt^T + bias.
// MODE 0: normal store (TC f32 or bf16). MODE 1: K-pack kt[b][h][c][dh^swz].
// MODE 2: V-pack vt[b][h][dh][c^swz]. For MODE 1/2 rows are (b,c), cols (h,dh).
template <typename TC, int MODE>
__global__ __launch_bounds__(256) void gemm128_k(
    const unsigned short* __restrict__ A, long lda,
    const unsigned short* __restrict__ Bt,
    const float* __restrict__ bias,
    TC* __restrict__ C, long ldc,
    long jsA, long jsW, long jsB, long jsC)
{
    __shared__ unsigned short As[128][64];   // [m][k] linear (global_load_lds dest)
    __shared__ unsigned short Bs[128][64];   // [n][k] linear

    const int tid = threadIdx.x;
    const int w = tid >> 6, lane = tid & 63;
    const long j = blockIdx.z;

    A    += (long)blockIdx.x * 128 * lda + j * jsA;
    Bt   += j * jsW + (long)blockIdx.y * 128 * 512;
    bias += j * jsB + blockIdx.y * 128;
    if constexpr (MODE == 0)
        C += (long)blockIdx.x * 128 * ldc + j * jsC + blockIdx.y * 128;

    const int srow = lane >> 3;
    const int scol = (lane & 7) * 8;
    const unsigned short* Ag = A  + (long)(w*8 + srow) * lda + scol;
    const unsigned short* Bg = Bt + (long)(w*8 + srow) * 512 + scol;
    char* Al = (char*)As + w * 1024;
    char* Bl = (char*)Bs + w * 1024;

    const int lr = lane & 15, lk = lane >> 4;
    const int wm = w >> 1, wn = w & 1;

    fx4 acc[4][4] = {};

    for (int kt = 0; kt < 512; kt += 64) {
        #pragma unroll
        for (int it = 0; it < 4; ++it)
            gload16(Ag + (long)it * 32 * lda + kt, Al + it * 4096);
        #pragma unroll
        for (int it = 0; it < 4; ++it)
            gload16(Bg + (long)it * 32 * 512 + kt, Bl + it * 4096);
        __syncthreads();
        #pragma unroll
        for (int ks = 0; ks < 2; ++ks) {
            s16x8 a[4], b[4];
            #pragma unroll
            for (int m = 0; m < 4; ++m)
                a[m] = *reinterpret_cast<const s16x8*>(&As[wm*64 + m*16 + lr][ks*32 + lk*8]);
            #pragma unroll
            for (int n = 0; n < 4; ++n)
                b[n] = *reinterpret_cast<const s16x8*>(&Bs[wn*64 + n*16 + lr][ks*32 + lk*8]);
            #pragma unroll
            for (int m = 0; m < 4; ++m)
                #pragma unroll
                for (int n = 0; n < 4; ++n)
                    acc[m][n] = mfma16(a[m], b[n], acc[m][n]);
        }
        __syncthreads();
    }

    // epilogue: C/D layout col=lane&15, row=(lane>>4)*4+r
    #pragma unroll
    for (int n = 0; n < 4; ++n) {
        const int col = wn*64 + n*16 + lr;
        const float bv = bias[col];
        #pragma unroll
        for (int m = 0; m < 4; ++m) {
            #pragma unroll
            for (int r = 0; r < 4; ++r) {
                const int row = wm*64 + m*16 + lk*4 + r;
                const float val = acc[m][n][r] + bv;
                if constexpr (MODE == 0) {
                    if constexpr (sizeof(TC) == 2)
                        reinterpret_cast<unsigned short*>(C)[(long)row*ldc + col] = f2bf(val);
                    else
                        reinterpret_cast<float*>(C)[(long)row*ldc + col] = val;
                } else {
                    const int grow = blockIdx.x*128 + row;       // (b, c)
                    const int gcol = blockIdx.y*128 + col;       // (h, dh)
                    const int b = grow >> 7, c = grow & 127;
                    const int hh = gcol >> 6, dh = gcol & 63;
                    unsigned short* Cp = reinterpret_cast<unsigned short*>(C);
                    if constexpr (MODE == 1) {
                        const int dhs = (dh & 7) | ((((dh >> 3) ^ (c & 7)) & 7) << 3);
                        Cp[(((long)b*8 + hh)*128 + c)*64 + dhs] = f2bf(val);
                    } else {
                        const int cs = (c & 7) | ((((c >> 3) ^ (dh & 7)) & 15) << 3);
                        Cp[(((long)b*8 + hh)*64 + dh)*128 + cs] = f2bf(val);
                    }
                }
            }
        }
    }
}

// ---------------------------------------------------------------------------
// Attention v2: one block per (q-tile of 128 rows, h, b). Rows span (t,n).
// K/V arrive packed + chunk-swizzled; staged linear via global_load_lds.
__global__ __launch_bounds__(256) void attn2_k(
    const unsigned short* __restrict__ q,   // bf16 [B, NR, 512]
    const unsigned short* __restrict__ kt,  // bf16 [B,H,128,64] swizzled
    const unsigned short* __restrict__ vt,  // bf16 [B,H,64,128] swizzled
    unsigned short* __restrict__ o)         // bf16 [B, NR, 512]
{
    __shared__ unsigned short Ps[128*136];  // P rows stride 136; first 8192 = Q[128][64]
    __shared__ unsigned short Ks[128*64];   // K [c][dh] swizzled
    __shared__ unsigned short Vs[64*128];   // V^T [dh][c] swizzled

    const int tid = threadIdx.x;
    const int w = tid >> 6, lane = tid & 63;
    const int lr = lane & 15, lk = lane >> 4;
    const int r0 = blockIdx.x * 128;
    const int h = blockIdx.y;
    const int b = blockIdx.z;

    const unsigned short* qg = q + ((long)b*NR + r0 + w*32 + (lane>>3))*512
                                 + h*64 + (lane & 7)*8;
    const unsigned short* kg = kt + ((long)(b*8+h))*8192 + (w*4)*512 + lane*8;
    const unsigned short* vg = vt + ((long)(b*8+h))*8192 + (w*4)*512 + lane*8;

    #pragma unroll
    for (int it = 0; it < 4; ++it) {
        gload16(qg + (long)it*8*512, (char*)Ps + (w*32 + it*8)*128);
        gload16(kg + it*512, (char*)Ks + (w*4 + it)*1024);
        gload16(vg + it*512, (char*)Vs + (w*4 + it)*1024);
    }
    __syncthreads();

    // Q fragments -> registers (wave owns rows w*32 .. w*32+31)
    s16x8 aq[2][2];
    #pragma unroll
    for (int m = 0; m < 2; ++m)
        #pragma unroll
        for (int kk = 0; kk < 2; ++kk)
            aq[m][kk] = *reinterpret_cast<const s16x8*>(
                &Ps[(w*32 + m*16 + lr)*64 + kk*32 + lk*8]);
    __syncthreads();   // Q consumed by ALL waves before P overwrites the buffer

    // S = Q K^T  (per wave: 32 rows x 128 cols)
    fx4 s[2][8] = {};
    #pragma unroll
    for (int kk = 0; kk < 2; ++kk) {
        #pragma unroll
        for (int f = 0; f < 8; ++f) {
            const int c = f*16 + lr;
            const int chunk = (kk*4 + lk) ^ (c & 7);
            s16x8 bk = *reinterpret_cast<const s16x8*>(&Ks[c*64 + chunk*8]);
            s[0][f] = mfma16(aq[0][kk], bk, s[0][f]);
            s[1][f] = mfma16(aq[1][kk], bk, s[1][f]);
        }
    }

    // wave-parallel softmax over C=128 (cols distributed across 16-lane groups)
    const float SC = 0.125f * 1.44269504088896340736f;   // scale * log2(e)
    #pragma unroll
    for (int m = 0; m < 2; ++m) {
        #pragma unroll
        for (int r = 0; r < 4; ++r) {
            float mx = -3.0e38f;
            #pragma unroll
            for (int f = 0; f < 8; ++f) mx = fmaxf(mx, s[m][f][r]);
            #pragma unroll
            for (int off = 1; off < 16; off <<= 1) mx = fmaxf(mx, __shfl_xor(mx, off));
            float p[8]; float sum = 0.f;
            #pragma unroll
            for (int f = 0; f < 8; ++f) {
                p[f] = exp2f((s[m][f][r] - mx) * SC);
                sum += p[f];
            }
            #pragma unroll
            for (int off = 1; off < 16; off <<= 1) sum += __shfl_xor(sum, off);
            const float inv = 1.0f / sum;
            const int row = w*32 + m*16 + lk*4 + r;
            #pragma unroll
            for (int f = 0; f < 8; ++f)
                Ps[row*136 + f*16 + lr] = f2bf(p[f] * inv);
        }
    }
    // no barrier: wave w's P rows are read only by wave w (lgkmcnt orders same-array ds ops)

    // O = P V  (K = 128 in 4 steps)
    fx4 oacc[2][4] = {};
    #pragma unroll
    for (int kt4 = 0; kt4 < 4; ++kt4) {
        s16x8 ap[2];
        #pragma unroll
        for (int m = 0; m < 2; ++m)
            ap[m] = *reinterpret_cast<const s16x8*>(
                &Ps[(w*32 + m*16 + lr)*136 + kt4*32 + lk*8]);
        #pragma unroll
        for (int bn = 0; bn < 4; ++bn) {
            const int dh = bn*16 + lr;
            const int chunk = (kt4*4 + lk) ^ (dh & 7);
            s16x8 bv = *reinterpret_cast<const s16x8*>(&Vs[dh*128 + chunk*8]);
            oacc[0][bn] = mfma16(ap[0], bv, oacc[0][bn]);
            oacc[1][bn] = mfma16(ap[1], bv, oacc[1][bn]);
        }
    }

    unsigned short* ob = o + ((long)b*NR + r0)*512 + h*64;
    #pragma unroll
    for (int m = 0; m < 2; ++m)
        #pragma unroll
        for (int bn = 0; bn < 4; ++bn)
            #pragma unroll
            for (int r = 0; r < 4; ++r) {
                const int row = w*32 + m*16 + lk*4 + r;
                ob[(long)row*512 + bn*16 + lr] = f2bf(oacc[m][bn][r]);
            }
}

extern "C" void kernel_launch(void* const* d_in, const int* in_sizes, int n_in,
                              void* d_out, int out_size, void* d_ws, size_t ws_size,
                              hipStream_t stream)
{
    const float* x    = (const float*)d_in[0];
    const float* ctx  = (const float*)d_in[1];
    const float* Wq   = (const float*)d_in[2];
    const float* bq   = (const float*)d_in[3];
    const float* Wk   = (const float*)d_in[4];
    const float* bk   = (const float*)d_in[5];
    const float* Wv   = (const float*)d_in[6];
    const float* bv   = (const float*)d_in[7];
    const float* Wout = (const float*)d_in[8];
    const float* bout = (const float*)d_in[9];
    float* out = (float*)d_out;

    const size_t NX  = (size_t)45056 * 512;   // x / q / o elements
    const size_t NKV = (size_t)4096 * 512;    // ctx / k / v elements
    const size_t NW  = (size_t)512 * 512;     // one weight matrix

    unsigned short* xbf   = (unsigned short*)d_ws;     // also obf
    unsigned short* qbf   = xbf   + NX;
    unsigned short* cbf   = qbf   + NX;                // ctx bf16
    unsigned short* ktp   = cbf   + NKV;               // packed swizzled K
    unsigned short* vtp   = ktp   + NKV;               // packed swizzled V^T
    unsigned short* WqT   = vtp   + NKV;               // 22 matrices, [n][k]
    unsigned short* WkT   = WqT   + 22 * NW;
    unsigned short* WvT   = WkT   + NW;
    unsigned short* WoutT = WvT   + NW;
    unsigned short* obf   = xbf;

    // 1) converts
    convx_k<<<dim3(NX / 2048), 256, 0, stream>>>(x, xbf);
    convx_k<<<dim3(NKV / 2048), 256, 0, stream>>>(ctx, cbf);
    twconv_k<<<dim3(8, 8, 22), 256, 0, stream>>>(Wq,   WqT,   (long)NW, (long)NW);
    twconv_k<<<dim3(8, 8, 1),  256, 0, stream>>>(Wk,   WkT,   0, 0);
    twconv_k<<<dim3(8, 8, 1),  256, 0, stream>>>(Wv,   WvT,   0, 0);
    twconv_k<<<dim3(8, 8, 1),  256, 0, stream>>>(Wout, WoutT, 0, 0);

    // 2) Q projection: per-joint (M=2048 rows, row stride NJ*ND)
    gemm128_k<unsigned short, 0><<<dim3(16, 4, NJ), 256, 0, stream>>>(
        xbf, (long)NJ*ND, WqT, bq, qbf, (long)NJ*ND,
        (long)ND, (long)NW, (long)ND, (long)ND);

    // 3,4) K/V projections: M = 4096, epilogue writes packed+swizzled layouts
    gemm128_k<unsigned short, 1><<<dim3(32, 4, 1), 256, 0, stream>>>(
        cbf, ND, WkT, bk, ktp, ND, 0, 0, 0, 0);
    gemm128_k<unsigned short, 2><<<dim3(32, 4, 1), 256, 0, stream>>>(
        cbf, ND, WvT, bv, vtp, ND, 0, 0, 0, 0);

    // 5) fused attention: one block per (q-tile, h, b)
    attn2_k<<<dim3(NR/128, NH, NB), 256, 0, stream>>>(qbf, ktp, vtp, obf);

    // 6) output projection: M = 45056, f32 output
    gemm128_k<float, 0><<<dim3(45056/128, 4, 1), 256, 0, stream>>>(
        obf, ND, WoutT, bout, out, ND, 0, 0, 0, 0);
}

// Round 5
// 207.803 us; speedup vs baseline: 1.6471x; 1.0278x over previous
//
#include <hip/hip_runtime.h>
#include <hip/hip_bf16.h>

// Problem dims
#define NB 32
#define NT 64
#define NJ 22
#define ND 512
#define NH 8
#define NC 128
#define NDH 64
#define NR 1408   // T*N rows per (b)

typedef __attribute__((ext_vector_type(8))) short s16x8;   // 8 bf16 (4 VGPRs)
typedef __attribute__((ext_vector_type(4))) float fx4;     // MFMA accumulator

static __device__ __forceinline__ unsigned short f2bf(float f) {
    unsigned u = __builtin_bit_cast(unsigned, f);
    u += 0x7fffu + ((u >> 16) & 1u);   // RNE
    return (unsigned short)(u >> 16);
}

static __device__ __forceinline__ fx4 mfma16(s16x8 a, s16x8 b, fx4 c) {
    return __builtin_amdgcn_mfma_f32_16x16x32_bf16(a, b, c, 0, 0, 0);
}

// async global->LDS, 16B per lane. LDS dest is wave-uniform base; HW adds lane*16.
static __device__ __forceinline__ void gload16(const void* g, void* l) {
    __builtin_amdgcn_global_load_lds(
        (const __attribute__((address_space(1))) void*)g,
        (__attribute__((address_space(3))) void*)l,
        16, 0, 0);
}

// ---------------------------------------------------------------------------
// f32 -> bf16 convert with chunk-XOR swizzle baked into the destination:
// within each 64-elem group of a 512-elem row, chunk c=(k>>3)&7 is stored at
// c ^ key, key = (flat_row / DIV) & 7.  DIV matches the consumer GEMM's row
// stride: DIV=1 for lda=512 consumers (ctx), DIV=NJ for the per-joint Q-proj
// (its logical row is bt = flat_row / NJ, de-swizzled with (tile_row & 7)).
template <int DIV>
__global__ __launch_bounds__(256) void convswz_k(const float* __restrict__ src,
                                                 unsigned short* __restrict__ dst)
{
    const long i = ((long)blockIdx.x * 256 + threadIdx.x) * 8;
    const unsigned row = (unsigned)(i >> 9);    // 512 elems per row
    const int  key = (int)((row / (unsigned)DIV) & 7u);
    const int  c   = (int)((i >> 3) & 7);
    const int  cs  = c ^ key;
    const long j   = (i & ~63L) | ((long)cs << 3);
    const float4 a = *reinterpret_cast<const float4*>(src + i);
    const float4 b = *reinterpret_cast<const float4*>(src + i + 4);
    unsigned short t[8];
    t[0]=f2bf(a.x); t[1]=f2bf(a.y); t[2]=f2bf(a.z); t[3]=f2bf(a.w);
    t[4]=f2bf(b.x); t[5]=f2bf(b.y); t[6]=f2bf(b.z); t[7]=f2bf(b.w);
    *reinterpret_cast<s16x8*>(dst + j) = *reinterpret_cast<s16x8*>(t);
}

// ---------------------------------------------------------------------------
// Wt[n][k] = (bf16) W[k][n], 512x512, with the same chunk-XOR swizzle on k
// (chunk ^ (n & 7)). blockIdx.z selects matrix.
__global__ __launch_bounds__(256) void twconv_k(const float* __restrict__ W,
                                                unsigned short* __restrict__ Wt,
                                                long zsrc, long zdst)
{
    __shared__ float T[64][65];
    const int tid = threadIdx.x;
    W  += blockIdx.z * zsrc + (long)blockIdx.x * 64 * 512 + blockIdx.y * 64;
    Wt += blockIdx.z * zdst + (long)blockIdx.y * 64 * 512 + blockIdx.x * 64;
    const int r = tid >> 2, c0 = (tid & 3) * 16;
    #pragma unroll
    for (int i = 0; i < 4; ++i) {
        const float4 p = *reinterpret_cast<const float4*>(W + (long)r * 512 + c0 + i*4);
        T[r][c0 + i*4 + 0] = p.x; T[r][c0 + i*4 + 1] = p.y;
        T[r][c0 + i*4 + 2] = p.z; T[r][c0 + i*4 + 3] = p.w;
    }
    __syncthreads();
    unsigned short o[16];
    #pragma unroll
    for (int i = 0; i < 16; ++i) o[i] = f2bf(T[c0 + i][r]);
    const int ch0 = ((c0 >> 3) ^ (r & 7));      // c0>>3 is even; second chunk = ch0^1
    *reinterpret_cast<s16x8*>(Wt + (long)r * 512 + ch0*8)       = *reinterpret_cast<s16x8*>(o);
    *reinterpret_cast<s16x8*>(Wt + (long)r * 512 + (ch0^1)*8)   = *reinterpret_cast<s16x8*>(o + 8);
}

// ---------------------------------------------------------------------------
// bf16 GEMM, 128x128 tile, BK=64, 4 waves, 2-phase double-buffered prefetch.
// A and Bt are chunk-XOR swizzled in global memory; LDS is linear
// (global_load_lds), ds_read applies the same XOR -> conflict-free.
// MODE 0: normal store. MODE 1: K-pack kt[b][h][c][dh^swz].
// MODE 2: V-pack vt[b][h][dh][c^swz].
template <typename TC, int MODE>
__global__ __launch_bounds__(256) void gemm128_k(
    const unsigned short* __restrict__ A, long lda,
    const unsigned short* __restrict__ Bt,
    const float* __restrict__ bias,
    TC* __restrict__ C, long ldc,
    long jsA, long jsW, long jsB, long jsC)
{
    __shared__ unsigned short As[2][128*64];
    __shared__ unsigned short Bs[2][128*64];

    const int tid = threadIdx.x;
    const int w = tid >> 6, lane = tid & 63;
    const long j = blockIdx.z;

    // XCD-aware bijective swizzle of the (x,y) grid (nwg % 8 == 0 always here)
    const int nx = gridDim.x;
    const int nwg = nx * gridDim.y;
    int lin = blockIdx.y * nx + blockIdx.x;
    lin = (lin & 7) * (nwg >> 3) + (lin >> 3);
    const int bx = lin % nx, by = lin / nx;

    A    += (long)bx * 128 * lda + j * jsA;
    Bt   += j * jsW + (long)by * 128 * 512;
    bias += j * jsB + by * 128;
    if constexpr (MODE == 0)
        C += (long)bx * 128 * ldc + j * jsC + by * 128;

    const int srow = lane >> 3;
    const int scol = (lane & 7) * 8;
    const unsigned short* Ag = A  + (long)(w*8 + srow) * lda + scol;
    const unsigned short* Bg = Bt + (long)(w*8 + srow) * 512 + scol;

    const int lr = lane & 15, lk = lane >> 4;
    const int wm = w >> 1, wn = w & 1;

    fx4 acc[4][4] = {};

    auto STAGE = [&](int buf, int kt) {
        char* Al = (char*)&As[buf][0] + w * 1024;
        char* Bl = (char*)&Bs[buf][0] + w * 1024;
        #pragma unroll
        for (int it = 0; it < 4; ++it)
            gload16(Ag + (long)it * 32 * lda + kt, Al + it * 4096);
        #pragma unroll
        for (int it = 0; it < 4; ++it)
            gload16(Bg + (long)it * 32 * 512 + kt, Bl + it * 4096);
    };

    auto COMPUTE = [&](int buf) {
        #pragma unroll
        for (int ks = 0; ks < 2; ++ks) {
            const int cha = (ks*4 + lk) ^ (lr & 7);   // same for A and B rows
            s16x8 a[4], b[4];
            #pragma unroll
            for (int m = 0; m < 4; ++m)
                a[m] = *reinterpret_cast<const s16x8*>(&As[buf][(wm*64 + m*16 + lr)*64 + cha*8]);
            #pragma unroll
            for (int n = 0; n < 4; ++n)
                b[n] = *reinterpret_cast<const s16x8*>(&Bs[buf][(wn*64 + n*16 + lr)*64 + cha*8]);
            #pragma unroll
            for (int m = 0; m < 4; ++m)
                #pragma unroll
                for (int n = 0; n < 4; ++n)
                    acc[m][n] = mfma16(a[m], b[n], acc[m][n]);
        }
    };

    // 2-phase pipeline over 8 K-tiles
    STAGE(0, 0);
    __syncthreads();            // drains vmcnt(0): tile 0 in LDS
    #pragma unroll
    for (int t = 0; t < 7; ++t) {
        const int cur = t & 1;
        STAGE(cur ^ 1, (t + 1) * 64);   // issue next tile's loads first
        COMPUTE(cur);                   // MFMA on current tile hides the loads
        __syncthreads();                // drain next-tile loads + reads of cur
    }
    COMPUTE(1);                 // tile 7

    // epilogue: C/D layout col=lane&15, row=(lane>>4)*4+r
    #pragma unroll
    for (int n = 0; n < 4; ++n) {
        const int col = wn*64 + n*16 + lr;
        const float bv = bias[col];
        #pragma unroll
        for (int m = 0; m < 4; ++m) {
            #pragma unroll
            for (int r = 0; r < 4; ++r) {
                const int row = wm*64 + m*16 + lk*4 + r;
                const float val = acc[m][n][r] + bv;
                if constexpr (MODE == 0) {
                    if constexpr (sizeof(TC) == 2)
                        reinterpret_cast<unsigned short*>(C)[(long)row*ldc + col] = f2bf(val);
                    else
                        reinterpret_cast<float*>(C)[(long)row*ldc + col] = val;
                } else {
                    const int grow = bx*128 + row;       // (b, c)
                    const int gcol = by*128 + col;       // (h, dh)
                    const int b = grow >> 7, c = grow & 127;
                    const int hh = gcol >> 6, dh = gcol & 63;
                    unsigned short* Cp = reinterpret_cast<unsigned short*>(C);
                    if constexpr (MODE == 1) {
                        const int dhs = (dh & 7) | ((((dh >> 3) ^ (c & 7)) & 7) << 3);
                        Cp[(((long)b*8 + hh)*128 + c)*64 + dhs] = f2bf(val);
                    } else {
                        const int cs = (c & 7) | ((((c >> 3) ^ (dh & 7)) & 15) << 3);
                        Cp[(((long)b*8 + hh)*64 + dh)*128 + cs] = f2bf(val);
                    }
                }
            }
        }
    }
}

// ---------------------------------------------------------------------------
// Attention: one block per (q-tile of 128 rows, h, b). Rows span (t,n).
// K/V arrive packed + chunk-swizzled; staged linear via global_load_lds.
// O is stored with the GEMM chunk-XOR swizzle (it feeds the out-proj GEMM).
__global__ __launch_bounds__(256) void attn2_k(
    const unsigned short* __restrict__ q,   // bf16 [B, NR, 512] linear
    const unsigned short* __restrict__ kt,  // bf16 [B,H,128,64] swizzled
    const unsigned short* __restrict__ vt,  // bf16 [B,H,64,128] swizzled
    unsigned short* __restrict__ o)         // bf16 [B, NR, 512] GEMM-swizzled
{
    __shared__ unsigned short Ps[128*136];  // P rows stride 136; first 8192 = Q[128][64]
    __shared__ unsigned short Ks[128*64];   // K [c][dh] swizzled
    __shared__ unsigned short Vs[64*128];   // V^T [dh][c] swizzled

    const int tid = threadIdx.x;
    const int w = tid >> 6, lane = tid & 63;
    const int lr = lane & 15, lk = lane >> 4;
    const int r0 = blockIdx.x * 128;
    const int h = blockIdx.y;
    const int b = blockIdx.z;

    const unsigned short* qg = q + ((long)b*NR + r0 + w*32 + (lane>>3))*512
                                 + h*64 + (lane & 7)*8;
    const unsigned short* kg = kt + ((long)(b*8+h))*8192 + (w*4)*512 + lane*8;
    const unsigned short* vg = vt + ((long)(b*8+h))*8192 + (w*4)*512 + lane*8;

    #pragma unroll
    for (int it = 0; it < 4; ++it) {
        gload16(qg + (long)it*8*512, (char*)Ps + (w*32 + it*8)*128);
        gload16(kg + it*512, (char*)Ks + (w*4 + it)*1024);
        gload16(vg + it*512, (char*)Vs + (w*4 + it)*1024);
    }
    __syncthreads();

    // Q fragments -> registers (wave owns rows w*32 .. w*32+31)
    s16x8 aq[2][2];
    #pragma unroll
    for (int m = 0; m < 2; ++m)
        #pragma unroll
        for (int kk = 0; kk < 2; ++kk)
            aq[m][kk] = *reinterpret_cast<const s16x8*>(
                &Ps[(w*32 + m*16 + lr)*64 + kk*32 + lk*8]);
    __syncthreads();   // Q consumed by ALL waves before P overwrites the buffer

    // S = Q K^T  (per wave: 32 rows x 128 cols)
    fx4 s[2][8] = {};
    #pragma unroll
    for (int kk = 0; kk < 2; ++kk) {
        #pragma unroll
        for (int f = 0; f < 8; ++f) {
            const int c = f*16 + lr;
            const int chunk = (kk*4 + lk) ^ (c & 7);
            s16x8 bk = *reinterpret_cast<const s16x8*>(&Ks[c*64 + chunk*8]);
            s[0][f] = mfma16(aq[0][kk], bk, s[0][f]);
            s[1][f] = mfma16(aq[1][kk], bk, s[1][f]);
        }
    }

    // wave-parallel softmax over C=128 (cols distributed across 16-lane groups)
    const float SC = 0.125f * 1.44269504088896340736f;   // scale * log2(e)
    #pragma unroll
    for (int m = 0; m < 2; ++m) {
        #pragma unroll
        for (int r = 0; r < 4; ++r) {
            float mx = -3.0e38f;
            #pragma unroll
            for (int f = 0; f < 8; ++f) mx = fmaxf(mx, s[m][f][r]);
            #pragma unroll
            for (int off = 1; off < 16; off <<= 1) mx = fmaxf(mx, __shfl_xor(mx, off));
            float p[8]; float sum = 0.f;
            #pragma unroll
            for (int f = 0; f < 8; ++f) {
                p[f] = exp2f((s[m][f][r] - mx) * SC);
                sum += p[f];
            }
            #pragma unroll
            for (int off = 1; off < 16; off <<= 1) sum += __shfl_xor(sum, off);
            const float inv = 1.0f / sum;
            const int row = w*32 + m*16 + lk*4 + r;
            #pragma unroll
            for (int f = 0; f < 8; ++f)
                Ps[row*136 + f*16 + lr] = f2bf(p[f] * inv);
        }
    }
    // no barrier: wave w's P rows are read only by wave w

    // O = P V  (K = 128 in 4 steps)
    fx4 oacc[2][4] = {};
    #pragma unroll
    for (int kt4 = 0; kt4 < 4; ++kt4) {
        s16x8 ap[2];
        #pragma unroll
        for (int m = 0; m < 2; ++m)
            ap[m] = *reinterpret_cast<const s16x8*>(
                &Ps[(w*32 + m*16 + lr)*136 + kt4*32 + lk*8]);
        #pragma unroll
        for (int bn = 0; bn < 4; ++bn) {
            const int dh = bn*16 + lr;
            const int chunk = (kt4*4 + lk) ^ (dh & 7);
            s16x8 bv = *reinterpret_cast<const s16x8*>(&Vs[dh*128 + chunk*8]);
            oacc[0][bn] = mfma16(ap[0], bv, oacc[0][bn]);
            oacc[1][bn] = mfma16(ap[1], bv, oacc[1][bn]);
        }
    }

    // store O with GEMM chunk-XOR swizzle (row & 7 on the 8-elem chunk index)
    unsigned short* ob = o + ((long)b*NR + r0)*512 + h*64;
    #pragma unroll
    for (int m = 0; m < 2; ++m)
        #pragma unroll
        for (int bn = 0; bn < 4; ++bn)
            #pragma unroll
            for (int r = 0; r < 4; ++r) {
                const int row = w*32 + m*16 + lk*4 + r;
                const int colg = bn*16 + lr;
                const int ch = ((colg >> 3) ^ (row & 7));
                ob[(long)row*512 + ch*8 + (lr & 7)] = f2bf(oacc[m][bn][r]);
            }
}

extern "C" void kernel_launch(void* const* d_in, const int* in_sizes, int n_in,
                              void* d_out, int out_size, void* d_ws, size_t ws_size,
                              hipStream_t stream)
{
    const float* x    = (const float*)d_in[0];
    const float* ctx  = (const float*)d_in[1];
    const float* Wq   = (const float*)d_in[2];
    const float* bq   = (const float*)d_in[3];
    const float* Wk   = (const float*)d_in[4];
    const float* bk   = (const float*)d_in[5];
    const float* Wv   = (const float*)d_in[6];
    const float* bv   = (const float*)d_in[7];
    const float* Wout = (const float*)d_in[8];
    const float* bout = (const float*)d_in[9];
    float* out = (float*)d_out;

    const size_t NX  = (size_t)45056 * 512;   // x / q / o elements
    const size_t NKV = (size_t)4096 * 512;    // ctx / k / v elements
    const size_t NW  = (size_t)512 * 512;     // one weight matrix

    unsigned short* xbf   = (unsigned short*)d_ws;     // also obf (both GEMM-swizzled)
    unsigned short* qbf   = xbf   + NX;                // linear
    unsigned short* cbf   = qbf   + NX;                // ctx bf16, GEMM-swizzled
    unsigned short* ktp   = cbf   + NKV;               // packed swizzled K
    unsigned short* vtp   = ktp   + NKV;               // packed swizzled V^T
    unsigned short* WqT   = vtp   + NKV;               // 22 matrices, [n][k] swizzled
    unsigned short* WkT   = WqT   + 22 * NW;
    unsigned short* WvT   = WkT   + NW;
    unsigned short* WoutT = WvT   + NW;
    unsigned short* obf   = xbf;

    // 1) converts (all GEMM operands get the chunk-XOR swizzle)
    // x: Q-proj reads rows strided by NJ -> key on bt = flat_row / NJ
    convswz_k<NJ><<<dim3(NX / 2048), 256, 0, stream>>>(x, xbf);
    // ctx: K/V-proj read lda=512 -> key on flat row
    convswz_k<1><<<dim3(NKV / 2048), 256, 0, stream>>>(ctx, cbf);
    twconv_k<<<dim3(8, 8, 22), 256, 0, stream>>>(Wq,   WqT,   (long)NW, (long)NW);
    twconv_k<<<dim3(8, 8, 1),  256, 0, stream>>>(Wk,   WkT,   0, 0);
    twconv_k<<<dim3(8, 8, 1),  256, 0, stream>>>(Wv,   WvT,   0, 0);
    twconv_k<<<dim3(8, 8, 1),  256, 0, stream>>>(Wout, WoutT, 0, 0);

    // 2) Q projection: per-joint (M=2048 rows, row stride NJ*ND)
    gemm128_k<unsigned short, 0><<<dim3(16, 4, NJ), 256, 0, stream>>>(
        xbf, (long)NJ*ND, WqT, bq, qbf, (long)NJ*ND,
        (long)ND, (long)NW, (long)ND, (long)ND);

    // 3,4) K/V projections: M = 4096, epilogue writes attn-packed layouts
    gemm128_k<unsigned short, 1><<<dim3(32, 4, 1), 256, 0, stream>>>(
        cbf, ND, WkT, bk, ktp, ND, 0, 0, 0, 0);
    gemm128_k<unsigned short, 2><<<dim3(32, 4, 1), 256, 0, stream>>>(
        cbf, ND, WvT, bv, vtp, ND, 0, 0, 0, 0);

    // 5) fused attention: one block per (q-tile, h, b)
    attn2_k<<<dim3(NR/128, NH, NB), 256, 0, stream>>>(qbf, ktp, vtp, obf);

    // 6) output projection: M = 45056, f32 output
    gemm128_k<float, 0><<<dim3(45056/128, 4, 1), 256, 0, stream>>>(
        obf, ND, WoutT, bout, out, ND, 0, 0, 0, 0);
}

// Round 6
// 200.592 us; speedup vs baseline: 1.7063x; 1.0360x over previous
//
#include <hip/hip_runtime.h>
#include <hip/hip_bf16.h>

// Problem dims
#define NB 32
#define NT 64
#define NJ 22
#define ND 512
#define NH 8
#define NC 128
#define NDH 64
#define NR 1408   // T*N rows per (b)

typedef __attribute__((ext_vector_type(8))) short s16x8;   // 8 bf16 (4 VGPRs)
typedef __attribute__((ext_vector_type(4))) float fx4;     // MFMA accumulator

static __device__ __forceinline__ unsigned short f2bf(float f) {
    unsigned u = __builtin_bit_cast(unsigned, f);
    u += 0x7fffu + ((u >> 16) & 1u);   // RNE
    return (unsigned short)(u >> 16);
}

static __device__ __forceinline__ fx4 mfma16(s16x8 a, s16x8 b, fx4 c) {
    return __builtin_amdgcn_mfma_f32_16x16x32_bf16(a, b, c, 0, 0, 0);
}

// async global->LDS, 16B per lane. LDS dest is wave-uniform base; HW adds lane*16.
static __device__ __forceinline__ void gload16(const void* g, void* l) {
    __builtin_amdgcn_global_load_lds(
        (const __attribute__((address_space(1))) void*)g,
        (__attribute__((address_space(3))) void*)l,
        16, 0, 0);
}

// ---------------------------------------------------------------------------
// f32 -> bf16 convert with chunk-XOR swizzle baked into the destination:
// within each 64-elem group of a 512-elem row, chunk c=(k>>3)&7 is stored at
// c ^ key, key = (flat_row / DIV) & 7.  DIV matches the consumer GEMM's row
// stride: DIV=1 for lda=512 consumers (ctx), DIV=NJ for the per-joint Q-proj.
template <int DIV>
__global__ __launch_bounds__(256) void convswz_k(const float* __restrict__ src,
                                                 unsigned short* __restrict__ dst)
{
    const long i = ((long)blockIdx.x * 256 + threadIdx.x) * 8;
    const unsigned row = (unsigned)(i >> 9);    // 512 elems per row
    const int  key = (int)((row / (unsigned)DIV) & 7u);
    const int  c   = (int)((i >> 3) & 7);
    const int  cs  = c ^ key;
    const long j   = (i & ~63L) | ((long)cs << 3);
    const float4 a = *reinterpret_cast<const float4*>(src + i);
    const float4 b = *reinterpret_cast<const float4*>(src + i + 4);
    unsigned short t[8];
    t[0]=f2bf(a.x); t[1]=f2bf(a.y); t[2]=f2bf(a.z); t[3]=f2bf(a.w);
    t[4]=f2bf(b.x); t[5]=f2bf(b.y); t[6]=f2bf(b.z); t[7]=f2bf(b.w);
    *reinterpret_cast<s16x8*>(dst + j) = *reinterpret_cast<s16x8*>(t);
}

// ---------------------------------------------------------------------------
// Wt[n][k] = (bf16) W[k][n], 512x512, with the same chunk-XOR swizzle on k
// (chunk ^ (n & 7)). blockIdx.z selects matrix.
__global__ __launch_bounds__(256) void twconv_k(const float* __restrict__ W,
                                                unsigned short* __restrict__ Wt,
                                                long zsrc, long zdst)
{
    __shared__ float T[64][65];
    const int tid = threadIdx.x;
    W  += blockIdx.z * zsrc + (long)blockIdx.x * 64 * 512 + blockIdx.y * 64;
    Wt += blockIdx.z * zdst + (long)blockIdx.y * 64 * 512 + blockIdx.x * 64;
    const int r = tid >> 2, c0 = (tid & 3) * 16;
    #pragma unroll
    for (int i = 0; i < 4; ++i) {
        const float4 p = *reinterpret_cast<const float4*>(W + (long)r * 512 + c0 + i*4);
        T[r][c0 + i*4 + 0] = p.x; T[r][c0 + i*4 + 1] = p.y;
        T[r][c0 + i*4 + 2] = p.z; T[r][c0 + i*4 + 3] = p.w;
    }
    __syncthreads();
    unsigned short o[16];
    #pragma unroll
    for (int i = 0; i < 16; ++i) o[i] = f2bf(T[c0 + i][r]);
    const int ch0 = ((c0 >> 3) ^ (r & 7));      // c0>>3 is even; second chunk = ch0^1
    *reinterpret_cast<s16x8*>(Wt + (long)r * 512 + ch0*8)       = *reinterpret_cast<s16x8*>(o);
    *reinterpret_cast<s16x8*>(Wt + (long)r * 512 + (ch0^1)*8)   = *reinterpret_cast<s16x8*>(o + 8);
}

// ---------------------------------------------------------------------------
// bf16 GEMM, 128x128 tile, BK=64, 4 waves, 2-phase double-buffered prefetch.
// A and Bt are chunk-XOR swizzled in global memory; LDS is linear
// (global_load_lds), ds_read applies the same XOR -> conflict-free.
// MODE 0: normal store. MODE 1: K-pack kt[b][h][c][dh^swz].
// MODE 2: V-pack vt[b][h][dh][c^swz].
template <typename TC, int MODE>
__global__ __launch_bounds__(256) void gemm128_k(
    const unsigned short* __restrict__ A, long lda,
    const unsigned short* __restrict__ Bt,
    const float* __restrict__ bias,
    TC* __restrict__ C, long ldc,
    long jsA, long jsW, long jsB, long jsC)
{
    __shared__ unsigned short As[2][128*64];
    __shared__ unsigned short Bs[2][128*64];

    const int tid = threadIdx.x;
    const int w = tid >> 6, lane = tid & 63;
    const long j = blockIdx.z;

    // XCD-aware bijective swizzle of the (x,y) grid (nwg % 8 == 0 always here)
    const int nx = gridDim.x;
    const int nwg = nx * gridDim.y;
    int lin = blockIdx.y * nx + blockIdx.x;
    lin = (lin & 7) * (nwg >> 3) + (lin >> 3);
    const int bx = lin % nx, by = lin / nx;

    A    += (long)bx * 128 * lda + j * jsA;
    Bt   += j * jsW + (long)by * 128 * 512;
    bias += j * jsB + by * 128;
    if constexpr (MODE == 0)
        C += (long)bx * 128 * ldc + j * jsC + by * 128;

    const int srow = lane >> 3;
    const int scol = (lane & 7) * 8;
    const unsigned short* Ag = A  + (long)(w*8 + srow) * lda + scol;
    const unsigned short* Bg = Bt + (long)(w*8 + srow) * 512 + scol;

    const int lr = lane & 15, lk = lane >> 4;
    const int wm = w >> 1, wn = w & 1;

    fx4 acc[4][4] = {};

    auto STAGE = [&](int buf, int kt) {
        char* Al = (char*)&As[buf][0] + w * 1024;
        char* Bl = (char*)&Bs[buf][0] + w * 1024;
        #pragma unroll
        for (int it = 0; it < 4; ++it)
            gload16(Ag + (long)it * 32 * lda + kt, Al + it * 4096);
        #pragma unroll
        for (int it = 0; it < 4; ++it)
            gload16(Bg + (long)it * 32 * 512 + kt, Bl + it * 4096);
    };

    auto COMPUTE = [&](int buf) {
        #pragma unroll
        for (int ks = 0; ks < 2; ++ks) {
            const int cha = (ks*4 + lk) ^ (lr & 7);   // same for A and B rows
            s16x8 a[4], b[4];
            #pragma unroll
            for (int m = 0; m < 4; ++m)
                a[m] = *reinterpret_cast<const s16x8*>(&As[buf][(wm*64 + m*16 + lr)*64 + cha*8]);
            #pragma unroll
            for (int n = 0; n < 4; ++n)
                b[n] = *reinterpret_cast<const s16x8*>(&Bs[buf][(wn*64 + n*16 + lr)*64 + cha*8]);
            #pragma unroll
            for (int m = 0; m < 4; ++m)
                #pragma unroll
                for (int n = 0; n < 4; ++n)
                    acc[m][n] = mfma16(a[m], b[n], acc[m][n]);
        }
    };

    // 2-phase pipeline over 8 K-tiles
    STAGE(0, 0);
    __syncthreads();            // drains vmcnt(0): tile 0 in LDS
    #pragma unroll
    for (int t = 0; t < 7; ++t) {
        const int cur = t & 1;
        STAGE(cur ^ 1, (t + 1) * 64);   // issue next tile's loads first
        COMPUTE(cur);                   // MFMA on current tile hides the loads
        __syncthreads();                // drain next-tile loads + reads of cur
    }
    COMPUTE(1);                 // tile 7

    // epilogue: C/D layout col=lane&15, row=(lane>>4)*4+r
    #pragma unroll
    for (int n = 0; n < 4; ++n) {
        const int col = wn*64 + n*16 + lr;
        const float bv = bias[col];
        #pragma unroll
        for (int m = 0; m < 4; ++m) {
            #pragma unroll
            for (int r = 0; r < 4; ++r) {
                const int row = wm*64 + m*16 + lk*4 + r;
                const float val = acc[m][n][r] + bv;
                if constexpr (MODE == 0) {
                    if constexpr (sizeof(TC) == 2)
                        reinterpret_cast<unsigned short*>(C)[(long)row*ldc + col] = f2bf(val);
                    else
                        reinterpret_cast<float*>(C)[(long)row*ldc + col] = val;
                } else {
                    const int grow = bx*128 + row;       // (b, c)
                    const int gcol = by*128 + col;       // (h, dh)
                    const int b = grow >> 7, c = grow & 127;
                    const int hh = gcol >> 6, dh = gcol & 63;
                    unsigned short* Cp = reinterpret_cast<unsigned short*>(C);
                    if constexpr (MODE == 1) {
                        const int dhs = (dh & 7) | ((((dh >> 3) ^ (c & 7)) & 7) << 3);
                        Cp[(((long)b*8 + hh)*128 + c)*64 + dhs] = f2bf(val);
                    } else {
                        const int cs = (c & 7) | ((((c >> 3) ^ (dh & 7)) & 15) << 3);
                        Cp[(((long)b*8 + hh)*64 + dh)*128 + cs] = f2bf(val);
                    }
                }
            }
        }
    }
}

// ---------------------------------------------------------------------------
// Attention v3: QBLK=64 (4 waves x 16 rows), 40KB LDS -> 4 blocks/CU.
// Regions: Qs[64][64] (8KB) | Ks[128][64] (16KB, becomes P[64][128] after
// QK^T) | Vs[64][128] (16KB). K/V/P chunk-XOR swizzled; only 2 barriers.
__global__ __launch_bounds__(256, 4) void attn3_k(
    const unsigned short* __restrict__ q,   // bf16 [B, NR, 512] linear
    const unsigned short* __restrict__ kt,  // bf16 [B,H,128,64] swizzled
    const unsigned short* __restrict__ vt,  // bf16 [B,H,64,128] swizzled
    unsigned short* __restrict__ o)         // bf16 [B, NR, 512] GEMM-swizzled
{
    __shared__ __align__(16) unsigned short smem[20480];   // 40960 B exactly
    unsigned short* Qs = smem;            // [64][64]
    unsigned short* Ks = smem + 4096;     // [128][64] swz; P[64][128] swz after
    unsigned short* Vs = smem + 12288;    // [64][128] swz

    const int tid = threadIdx.x;
    const int w = tid >> 6, lane = tid & 63;
    const int lr = lane & 15, lk = lane >> 4;
    const int r0 = blockIdx.x * 64;
    const int h = blockIdx.y;
    const int b = blockIdx.z;

    const unsigned short* qg = q + ((long)b*NR + r0 + w*16 + (lane>>3))*512
                                 + h*64 + (lane & 7)*8;
    const unsigned short* kg = kt + ((long)(b*8+h))*8192 + w*2048 + lane*8;
    const unsigned short* vg = vt + ((long)(b*8+h))*8192 + w*2048 + lane*8;

    // stage: Q 2 + K 4 + V 4 gload16 per wave
    gload16(qg,            (char*)Qs + w*2048);
    gload16(qg + 8*512,    (char*)Qs + w*2048 + 1024);
    #pragma unroll
    for (int it = 0; it < 4; ++it) {
        gload16(kg + it*512, (char*)Ks + w*4096 + it*1024);
        gload16(vg + it*512, (char*)Vs + w*4096 + it*1024);
    }
    __syncthreads();

    // Q fragments (wave owns rows w*16 .. w*16+15)
    s16x8 aq[2];
    #pragma unroll
    for (int kk = 0; kk < 2; ++kk)
        aq[kk] = *reinterpret_cast<const s16x8*>(&Qs[(w*16 + lr)*64 + kk*32 + lk*8]);

    // S = Q K^T  (16 x 128 per wave)
    fx4 s[8] = {};
    #pragma unroll
    for (int kk = 0; kk < 2; ++kk) {
        #pragma unroll
        for (int f = 0; f < 8; ++f) {
            const int c = f*16 + lr;
            const int chunk = (kk*4 + lk) ^ (c & 7);
            s16x8 bk = *reinterpret_cast<const s16x8*>(&Ks[c*64 + chunk*8]);
            s[f] = mfma16(aq[kk], bk, s[f]);
        }
    }
    __syncthreads();   // all waves done reading Ks; region becomes P

    unsigned short* P = Ks;   // [64][128], chunk-XOR (chunk ^ (row & 7))

    // wave-parallel softmax over C=128; P rows written are wave-own
    const float SC = 0.125f * 1.44269504088896340736f;   // scale * log2(e)
    #pragma unroll
    for (int rr = 0; rr < 4; ++rr) {
        const int row = w*16 + lk*4 + rr;
        float mx = -3.0e38f;
        #pragma unroll
        for (int f = 0; f < 8; ++f) mx = fmaxf(mx, s[f][rr]);
        #pragma unroll
        for (int off = 1; off < 16; off <<= 1) mx = fmaxf(mx, __shfl_xor(mx, off));
        float p[8]; float sum = 0.f;
        #pragma unroll
        for (int f = 0; f < 8; ++f) {
            p[f] = exp2f((s[f][rr] - mx) * SC);
            sum += p[f];
        }
        #pragma unroll
        for (int off = 1; off < 16; off <<= 1) sum += __shfl_xor(sum, off);
        const float inv = 1.0f / sum;
        #pragma unroll
        for (int f = 0; f < 8; ++f) {
            const int cg = f*16 + lr;
            P[row*128 + (((cg >> 3) ^ (row & 7)) << 3) + (cg & 7)] = f2bf(p[f] * inv);
        }
    }
    // no barrier: wave reads back only its own P rows

    // O = P V  (16 x 64 per wave, K = 128)
    fx4 oacc[4] = {};
    #pragma unroll
    for (int kt4 = 0; kt4 < 4; ++kt4) {
        const int prow = w*16 + lr;
        s16x8 ap = *reinterpret_cast<const s16x8*>(
            &P[prow*128 + (((kt4*4 + lk) ^ (prow & 7)) << 3)]);
        #pragma unroll
        for (int bn = 0; bn < 4; ++bn) {
            const int dh = bn*16 + lr;
            const int chunk = (kt4*4 + lk) ^ (dh & 7);
            s16x8 bv = *reinterpret_cast<const s16x8*>(&Vs[dh*128 + chunk*8]);
            oacc[bn] = mfma16(ap, bv, oacc[bn]);
        }
    }

    // store O with GEMM chunk-XOR swizzle (row & 7 on the 8-elem chunk index)
    unsigned short* ob = o + ((long)b*NR + r0)*512 + h*64;
    #pragma unroll
    for (int bn = 0; bn < 4; ++bn)
        #pragma unroll
        for (int rr = 0; rr < 4; ++rr) {
            const int row = w*16 + lk*4 + rr;
            const int colg = bn*16 + lr;
            const int ch = ((colg >> 3) ^ (row & 7));
            ob[(long)row*512 + ch*8 + (lr & 7)] = f2bf(oacc[bn][rr]);
        }
}

extern "C" void kernel_launch(void* const* d_in, const int* in_sizes, int n_in,
                              void* d_out, int out_size, void* d_ws, size_t ws_size,
                              hipStream_t stream)
{
    const float* x    = (const float*)d_in[0];
    const float* ctx  = (const float*)d_in[1];
    const float* Wq   = (const float*)d_in[2];
    const float* bq   = (const float*)d_in[3];
    const float* Wk   = (const float*)d_in[4];
    const float* bk   = (const float*)d_in[5];
    const float* Wv   = (const float*)d_in[6];
    const float* bv   = (const float*)d_in[7];
    const float* Wout = (const float*)d_in[8];
    const float* bout = (const float*)d_in[9];
    float* out = (float*)d_out;

    const size_t NX  = (size_t)45056 * 512;   // x / q / o elements
    const size_t NKV = (size_t)4096 * 512;    // ctx / k / v elements
    const size_t NW  = (size_t)512 * 512;     // one weight matrix

    unsigned short* xbf   = (unsigned short*)d_ws;     // also obf (both GEMM-swizzled)
    unsigned short* qbf   = xbf   + NX;                // linear
    unsigned short* cbf   = qbf   + NX;                // ctx bf16, GEMM-swizzled
    unsigned short* ktp   = cbf   + NKV;               // packed swizzled K
    unsigned short* vtp   = ktp   + NKV;               // packed swizzled V^T
    unsigned short* WqT   = vtp   + NKV;               // 22 matrices, [n][k] swizzled
    unsigned short* WkT   = WqT   + 22 * NW;
    unsigned short* WvT   = WkT   + NW;
    unsigned short* WoutT = WvT   + NW;
    unsigned short* obf   = xbf;

    // 1) converts (all GEMM operands get the chunk-XOR swizzle)
    convswz_k<NJ><<<dim3(NX / 2048), 256, 0, stream>>>(x, xbf);
    convswz_k<1><<<dim3(NKV / 2048), 256, 0, stream>>>(ctx, cbf);
    twconv_k<<<dim3(8, 8, 22), 256, 0, stream>>>(Wq,   WqT,   (long)NW, (long)NW);
    twconv_k<<<dim3(8, 8, 1),  256, 0, stream>>>(Wk,   WkT,   0, 0);
    twconv_k<<<dim3(8, 8, 1),  256, 0, stream>>>(Wv,   WvT,   0, 0);
    twconv_k<<<dim3(8, 8, 1),  256, 0, stream>>>(Wout, WoutT, 0, 0);

    // 2) Q projection: per-joint (M=2048 rows, row stride NJ*ND)
    gemm128_k<unsigned short, 0><<<dim3(16, 4, NJ), 256, 0, stream>>>(
        xbf, (long)NJ*ND, WqT, bq, qbf, (long)NJ*ND,
        (long)ND, (long)NW, (long)ND, (long)ND);

    // 3,4) K/V projections: M = 4096, epilogue writes attn-packed layouts
    gemm128_k<unsigned short, 1><<<dim3(32, 4, 1), 256, 0, stream>>>(
        cbf, ND, WkT, bk, ktp, ND, 0, 0, 0, 0);
    gemm128_k<unsigned short, 2><<<dim3(32, 4, 1), 256, 0, stream>>>(
        cbf, ND, WvT, bv, vtp, ND, 0, 0, 0, 0);

    // 5) fused attention: one block per (64-row q-tile, h, b)
    attn3_k<<<dim3(NR/64, NH, NB), 256, 0, stream>>>(qbf, ktp, vtp, obf);

    // 6) output projection: M = 45056, f32 output
    gemm128_k<float, 0><<<dim3(45056/128, 4, 1), 256, 0, stream>>>(
        obf, ND, WoutT, bout, out, ND, 0, 0, 0, 0);
}